// Round 1
// baseline (46.631 us; speedup 1.0000x reference)
//
#include <hip/hip_runtime.h>

// Shared_Unit_NL (KG-MTL-C variant):
//   s_cnn[b] = <drug_kg[b], w_aa + w_ab>
//   s_kg [b] = <drug_kg[b], w_ba + w_bb>
//   out_cnn[b,i] = drug_cnn[b,i] * s_cnn[b] + d_cnn_bias[i]
//   out_kg [b,i] = drug_cnn[b,i] * s_kg [b] + d_kg_bias[i]
// All fp32. B=65536, D=256. Memory-bound: 256 MB moved -> ~41 us floor.

constexpr int BN = 65536;
constexpr int DN = 256;

__global__ __launch_bounds__(256) void shared_unit_kernel(
    const float* __restrict__ drug_cnn,
    const float* __restrict__ drug_kg,
    const float* __restrict__ w_aa,
    const float* __restrict__ w_ab,
    const float* __restrict__ w_ba,
    const float* __restrict__ w_bb,
    const float* __restrict__ bias_cnn,
    const float* __restrict__ bias_kg,
    float* __restrict__ out)
{
    const int lane = threadIdx.x & 63;
    const int wid  = (blockIdx.x * blockDim.x + threadIdx.x) >> 6;  // global wave id
    const int nw   = (gridDim.x * blockDim.x) >> 6;                 // total waves
    const int j    = lane << 2;  // element offset within a row (4 floats/lane * 64 lanes = 256 = D)

    // Hoisted row-invariant data (tiny, L1-resident).
    const float4 waa = *(const float4*)(w_aa + j);
    const float4 wab = *(const float4*)(w_ab + j);
    const float4 wba = *(const float4*)(w_ba + j);
    const float4 wbb = *(const float4*)(w_bb + j);
    const float4 wa  = make_float4(waa.x + wab.x, waa.y + wab.y, waa.z + wab.z, waa.w + wab.w);
    const float4 wb  = make_float4(wba.x + wbb.x, wba.y + wbb.y, wba.z + wbb.z, wba.w + wbb.w);
    const float4 bc  = *(const float4*)(bias_cnn + j);
    const float4 bk  = *(const float4*)(bias_kg + j);

    float* __restrict__ out_cnn = out;
    float* __restrict__ out_kg  = out + (size_t)BN * DN;

    for (int b = wid; b < BN; b += nw) {
        const size_t base = (size_t)b * DN + j;

        const float4 kg  = *(const float4*)(drug_kg  + base);
        const float4 cnn = *(const float4*)(drug_cnn + base);  // issued early for ILP

        float sa = kg.x * wa.x + kg.y * wa.y + kg.z * wa.z + kg.w * wa.w;
        float sb = kg.x * wb.x + kg.y * wb.y + kg.z * wb.z + kg.w * wb.w;

        // 64-lane butterfly reduce (wave = 64 on CDNA!); all lanes end with the sum.
        #pragma unroll
        for (int off = 1; off < 64; off <<= 1) {
            sa += __shfl_xor(sa, off);
            sb += __shfl_xor(sb, off);
        }

        const float4 oc = make_float4(cnn.x * sa + bc.x, cnn.y * sa + bc.y,
                                      cnn.z * sa + bc.z, cnn.w * sa + bc.w);
        const float4 ok = make_float4(cnn.x * sb + bk.x, cnn.y * sb + bk.y,
                                      cnn.z * sb + bk.z, cnn.w * sb + bk.w);

        *(float4*)(out_cnn + base) = oc;
        *(float4*)(out_kg  + base) = ok;
    }
}

extern "C" void kernel_launch(void* const* d_in, const int* in_sizes, int n_in,
                              void* d_out, int out_size, void* d_ws, size_t ws_size,
                              hipStream_t stream) {
    const float* drug_cnn = (const float*)d_in[0];
    const float* drug_kg  = (const float*)d_in[1];
    const float* w_aa     = (const float*)d_in[2];
    const float* w_ab     = (const float*)d_in[3];
    const float* w_ba     = (const float*)d_in[4];
    const float* w_bb     = (const float*)d_in[5];
    const float* b_cnn    = (const float*)d_in[6];
    const float* b_kg     = (const float*)d_in[7];
    float* out = (float*)d_out;

    // 2048 blocks x 256 threads = 8192 waves; 8 rows per wave grid-stride.
    // 8 blocks/CU -> full 32-wave occupancy to hide the shuffle-reduce chain.
    dim3 grid(2048), block(256);
    hipLaunchKernelGGL(shared_unit_kernel, grid, block, 0, stream,
                       drug_cnn, drug_kg, w_aa, w_ab, w_ba, w_bb, b_cnn, b_kg, out);
}